// Round 10
// baseline (350.517 us; speedup 1.0000x reference)
//
#include <hip/hip_runtime.h>
#include <hip/hip_bf16.h>
#include <math.h>

// Problem constants
#define B_  2
#define K_  512
#define SD_ 60
#define NA_ 5
#define E_  256
#define H_  4
#define D_  64
#define FF_ 1024
#define NL_ 2
#define L_  (3 * K_)          // 1536 tokens per batch
#define M_  (B_ * L_)         // 3072 rows total
#define EPS_F 1e-6f
#define LN_EPS 1e-5f
#define CHK 64
#define NC_ (L_ / CHK)        // 24 chunks per (b,h)

using bf16x8 = __attribute__((ext_vector_type(8))) short;
using f32x4  = __attribute__((ext_vector_type(4))) float;
typedef unsigned short u16;

__device__ inline u16 f2b(float v) {
    __hip_bfloat16 h = __float2bfloat16(v);
    return *(u16*)&h;
}
__device__ inline float b2f(u16 v) {
    __hip_bfloat16 h = *(__hip_bfloat16*)&v;
    return __bfloat162float(h);
}

// ---------------------------------------------------------------------------
// Init kernel: blocks 0..1535 = weight convert+transpose (32x32 tiles),
//              blocks 1536..2303 = embed + interleave + LN1(layer0)
// ---------------------------------------------------------------------------
__global__ __launch_bounds__(256) void init_kernel(
    const float* __restrict__ qkv_w, const float* __restrict__ out_w,
    const float* __restrict__ ffn1_w, const float* __restrict__ ffn2_w,
    u16* __restrict__ qkvT, u16* __restrict__ outT,
    u16* __restrict__ f1T, u16* __restrict__ f2T,
    const float* __restrict__ rtg, const float* __restrict__ state,
    const float* __restrict__ action,
    const float* __restrict__ rtg_w, const float* __restrict__ rtg_b,
    const float* __restrict__ state_w, const float* __restrict__ state_b,
    const float* __restrict__ action_w, const float* __restrict__ action_b,
    const float* __restrict__ pos,
    const float* __restrict__ g, const float* __restrict__ bta,
    float* __restrict__ X, u16* __restrict__ Y)
{
    __shared__ u16 T[32][33];
    if (blockIdx.x < 1536) {
        int tb = blockIdx.x;
        int layer = tb / 768;
        int r = tb % 768;
        const float* src; u16* dst; int K, N, tidx;
        if (r < 192)      { src = qkv_w  + layer * 196608; dst = qkvT + layer * 196608; K = 256;  N = 768;  tidx = r; }
        else if (r < 256) { src = out_w  + layer * 65536;  dst = outT + layer * 65536;  K = 256;  N = 256;  tidx = r - 192; }
        else if (r < 512) { src = ffn1_w + layer * 262144; dst = f1T  + layer * 262144; K = 256;  N = 1024; tidx = r - 256; }
        else              { src = ffn2_w + layer * 262144; dst = f2T  + layer * 262144; K = 1024; N = 256;  tidx = r - 512; }
        int tilesN = N >> 5;
        int k0 = (tidx / tilesN) << 5;
        int n0 = (tidx % tilesN) << 5;
        int c = threadIdx.x & 31, r0 = threadIdx.x >> 5;
        for (int rr = r0; rr < 32; rr += 8)
            T[rr][c] = f2b(src[(size_t)(k0 + rr) * N + n0 + c]);
        __syncthreads();
        for (int rr = r0; rr < 32; rr += 8)
            dst[(size_t)(n0 + rr) * K + k0 + c] = T[c][rr];
        return;
    }
    // embed + LN1(layer0)
    int tok = (blockIdx.x - 1536) * 4 + (threadIdx.x >> 6);
    int lane = threadIdx.x & 63;
    int b = tok / L_, l = tok % L_;
    int j = l % 3, t = l / 3;
    int e0 = lane * 4;
    float4 val = *(const float4*)(pos + t * E_ + e0);
    if (j == 0) {
        float rv = rtg[b * K_ + t];
        float4 w = *(const float4*)(rtg_w + e0);
        float4 bb = *(const float4*)(rtg_b + e0);
        val.x += rv * w.x + bb.x; val.y += rv * w.y + bb.y;
        val.z += rv * w.z + bb.z; val.w += rv * w.w + bb.w;
    } else if (j == 1) {
        float4 a = *(const float4*)(state_b + e0);
        const float* srow = state + ((size_t)b * K_ + t) * SD_;
        for (int i = 0; i < SD_; i++) {
            float s = srow[i];
            float4 w = *(const float4*)(state_w + (size_t)i * E_ + e0);
            a.x += s * w.x; a.y += s * w.y; a.z += s * w.z; a.w += s * w.w;
        }
        val.x += a.x; val.y += a.y; val.z += a.z; val.w += a.w;
    } else {
        float4 a = *(const float4*)(action_b + e0);
        const float* arow = action + ((size_t)b * K_ + t) * NA_;
        #pragma unroll
        for (int i = 0; i < NA_; i++) {
            float s = arow[i];
            float4 w = *(const float4*)(action_w + (size_t)i * E_ + e0);
            a.x += s * w.x; a.y += s * w.y; a.z += s * w.z; a.w += s * w.w;
        }
        val.x += a.x; val.y += a.y; val.z += a.z; val.w += a.w;
    }
    *(float4*)(X + (size_t)tok * E_ + e0) = val;
    float s = val.x + val.y + val.z + val.w;
    #pragma unroll
    for (int o = 32; o; o >>= 1) s += __shfl_xor(s, o, 64);
    float mean = s * (1.f / E_);
    float dx = val.x - mean, dy = val.y - mean, dz = val.z - mean, dw = val.w - mean;
    float q = dx * dx + dy * dy + dz * dz + dw * dw;
    #pragma unroll
    for (int o = 32; o; o >>= 1) q += __shfl_xor(q, o, 64);
    float inv = rsqrtf(q * (1.f / E_) + LN_EPS);
    float4 gv = *(const float4*)(g + e0);
    float4 bv = *(const float4*)(bta + e0);
    ushort4 u;
    u.x = f2b(dx * inv * gv.x + bv.x); u.y = f2b(dy * inv * gv.y + bv.y);
    u.z = f2b(dz * inv * gv.z + bv.z); u.w = f2b(dw * inv * gv.w + bv.w);
    *(ushort4*)(Y + (size_t)tok * E_ + e0) = u;
}

// ---------------------------------------------------------------------------
// LayerNorm over E=256; one wave per token, fp32 in, bf16 out
// ---------------------------------------------------------------------------
__global__ __launch_bounds__(256) void ln_kernel(
    const float* __restrict__ X, const float* __restrict__ g,
    const float* __restrict__ b, u16* __restrict__ Y)
{
    int tok = blockIdx.x * 4 + (threadIdx.x >> 6);
    int lane = threadIdx.x & 63;
    int e0 = lane * 4;
    float4 v = *(const float4*)(X + (size_t)tok * E_ + e0);
    float s = v.x + v.y + v.z + v.w;
    #pragma unroll
    for (int o = 32; o; o >>= 1) s += __shfl_xor(s, o, 64);
    float mean = s * (1.f / E_);
    float dx = v.x - mean, dy = v.y - mean, dz = v.z - mean, dw = v.w - mean;
    float q = dx * dx + dy * dy + dz * dz + dw * dw;
    #pragma unroll
    for (int o = 32; o; o >>= 1) q += __shfl_xor(q, o, 64);
    float inv = rsqrtf(q * (1.f / E_) + LN_EPS);
    float4 gv = *(const float4*)(g + e0);
    float4 bv = *(const float4*)(b + e0);
    ushort4 u;
    u.x = f2b(dx * inv * gv.x + bv.x); u.y = f2b(dy * inv * gv.y + bv.y);
    u.z = f2b(dz * inv * gv.z + bv.z); u.w = f2b(dw * inv * gv.w + bv.w);
    *(ushort4*)(Y + (size_t)tok * E_ + e0) = u;
}

// ---------------------------------------------------------------------------
// MFMA bf16 GEMM: C[M,N] = epi(A[M,K]bf16 @ Bt[N,K]bf16^T + bias), bf16 out
// 128x128 tile, 256 threads = 4 waves (2x2 of 64x64), BK=64 (fewer barriers)
// EPI: 0 none, 1 exact gelu
// ---------------------------------------------------------------------------
template <int EPI>
__global__ __launch_bounds__(256) void mgemm(
    const u16* __restrict__ A, const u16* __restrict__ Bt,
    const float* __restrict__ bias,
    u16* __restrict__ C, int M, int N, int Kd)
{
    __shared__ __align__(16) u16 As[128 * 72];
    __shared__ __align__(16) u16 Bs[128 * 72];
    int tid = threadIdx.x;
    int bm = blockIdx.y * 128, bn = blockIdx.x * 128;
    int wave = tid >> 6, lane = tid & 63;
    int wm = (wave >> 1) * 64, wn = (wave & 1) * 64;
    int lr = lane & 15, kg = lane >> 4;

    f32x4 acc[4][4] = {};

    for (int k0 = 0; k0 < Kd; k0 += 64) {
        // 128 rows x 64 k of u16 = 1024 16B segs per matrix; 4 per thread
        uint4 av[4], bv[4];
        #pragma unroll
        for (int s = 0; s < 4; s++) {
            int seg = tid + 256 * s;
            int row = seg >> 3, koff = (seg & 7) * 8;
            av[s] = *(const uint4*)(A + (size_t)(bm + row) * Kd + k0 + koff);
            bv[s] = *(const uint4*)(Bt + (size_t)(bn + row) * Kd + k0 + koff);
        }
        __syncthreads();
        #pragma unroll
        for (int s = 0; s < 4; s++) {
            int seg = tid + 256 * s;
            int row = seg >> 3, koff = (seg & 7) * 8;
            *(uint4*)&As[row * 72 + koff] = av[s];
            *(uint4*)&Bs[row * 72 + koff] = bv[s];
        }
        __syncthreads();
        #pragma unroll
        for (int sub = 0; sub < 64; sub += 32) {
            bf16x8 af[4], bg[4];
            #pragma unroll
            for (int i = 0; i < 4; i++)
                af[i] = *(const bf16x8*)&As[(wm + i * 16 + lr) * 72 + sub + kg * 8];
            #pragma unroll
            for (int j = 0; j < 4; j++)
                bg[j] = *(const bf16x8*)&Bs[(wn + j * 16 + lr) * 72 + sub + kg * 8];
            #pragma unroll
            for (int i = 0; i < 4; i++)
                #pragma unroll
                for (int j = 0; j < 4; j++)
                    acc[i][j] = __builtin_amdgcn_mfma_f32_16x16x32_bf16(
                        af[i], bg[j], acc[i][j], 0, 0, 0);
        }
    }

    #pragma unroll
    for (int i = 0; i < 4; i++) {
        #pragma unroll
        for (int j = 0; j < 4; j++) {
            int col = bn + wn + j * 16 + lr;
            float bc = bias[col];
            #pragma unroll
            for (int r = 0; r < 4; r++) {
                int row = bm + wm + i * 16 + kg * 4 + r;
                float v = acc[i][j][r] + bc;
                if (EPI == 1) v = 0.5f * v * (1.0f + erff(v * 0.70710678118654752f));
                C[(size_t)row * N + col] = f2b(v);
            }
        }
    }
}

// ---------------------------------------------------------------------------
// 64x64-tile MFMA GEMM + residual accumulate into fp32 X. N=256 fixed.
// 192 tiles (M/64 x 4); 4 waves as 2x2 of 32x32. BK=64.
// ---------------------------------------------------------------------------
__global__ __launch_bounds__(256) void gemm64res(
    const u16* __restrict__ A, const u16* __restrict__ Bt,
    const float* __restrict__ bias, float* __restrict__ X, int Kd)
{
    __shared__ __align__(16) u16 As[64 * 72];
    __shared__ __align__(16) u16 Bs[64 * 72];
    int tid = threadIdx.x;
    int tile = blockIdx.x;
    int bm = (tile >> 2) * 64, bn = (tile & 3) * 64;
    int wave = tid >> 6, lane = tid & 63;
    int wm = (wave >> 1) * 32, wn = (wave & 1) * 32;
    int lr = lane & 15, kg = lane >> 4;

    f32x4 acc[2][2] = {};
    for (int k0 = 0; k0 < Kd; k0 += 64) {
        // 64 rows x 64 k = 512 16B segs per matrix; 2 per thread
        uint4 av[2], bv[2];
        #pragma unroll
        for (int s = 0; s < 2; s++) {
            int seg = tid + 256 * s;
            int row = seg >> 3, koff = (seg & 7) * 8;
            av[s] = *(const uint4*)(A + (size_t)(bm + row) * Kd + k0 + koff);
            bv[s] = *(const uint4*)(Bt + (size_t)(bn + row) * Kd + k0 + koff);
        }
        __syncthreads();
        #pragma unroll
        for (int s = 0; s < 2; s++) {
            int seg = tid + 256 * s;
            int row = seg >> 3, koff = (seg & 7) * 8;
            *(uint4*)&As[row * 72 + koff] = av[s];
            *(uint4*)&Bs[row * 72 + koff] = bv[s];
        }
        __syncthreads();
        #pragma unroll
        for (int sub = 0; sub < 64; sub += 32) {
            bf16x8 af[2], bg[2];
            #pragma unroll
            for (int i = 0; i < 2; i++)
                af[i] = *(const bf16x8*)&As[(wm + i * 16 + lr) * 72 + sub + kg * 8];
            #pragma unroll
            for (int j = 0; j < 2; j++)
                bg[j] = *(const bf16x8*)&Bs[(wn + j * 16 + lr) * 72 + sub + kg * 8];
            #pragma unroll
            for (int i = 0; i < 2; i++)
                #pragma unroll
                for (int j = 0; j < 2; j++)
                    acc[i][j] = __builtin_amdgcn_mfma_f32_16x16x32_bf16(
                        af[i], bg[j], acc[i][j], 0, 0, 0);
        }
    }
    #pragma unroll
    for (int i = 0; i < 2; i++) {
        #pragma unroll
        for (int j = 0; j < 2; j++) {
            int col = bn + wn + j * 16 + lr;
            float bc = bias[col];
            #pragma unroll
            for (int rr = 0; rr < 4; rr++) {
                int row = bm + wm + i * 16 + kg * 4 + rr;
                float v = acc[i][j][rr] + bc + X[(size_t)row * 256 + col];
                X[(size_t)row * 256 + col] = v;
            }
        }
    }
}

// ---------------------------------------------------------------------------
// Chunked linear attention; qkv bf16: (B,L,768) q|k|v head-major D=64
// Pass A: per-chunk S[d][e] = sum_t k[t][d] v[t][e], z[d] = sum_t k[t][d]
// ---------------------------------------------------------------------------
__global__ __launch_bounds__(256) void chunk_sum_kernel(
    const u16* __restrict__ QKV, float* __restrict__ S, float* __restrict__ Z)
{
    int blk = blockIdx.x;                  // (b*H+h)*NC + c
    int c = blk % NC_;
    int bh = blk / NC_;
    int h = bh % H_;
    int b = bh / H_;
    __shared__ __align__(16) u16 Kt[64 * 72];   // [d][t]
    __shared__ __align__(16) u16 Vt[64 * 72];   // [e][t]
    int tid = threadIdx.x;
    const size_t base = ((size_t)b * L_ + (size_t)c * CHK) * 768 + h * 64;
    for (int i = tid; i < 1024; i += 256) {
        int t = i >> 4, d4 = (i & 15) << 2;
        ushort4 k = *(const ushort4*)(QKV + base + (size_t)t * 768 + 256 + d4);
        ushort4 v = *(const ushort4*)(QKV + base + (size_t)t * 768 + 512 + d4);
        Kt[(d4 + 0) * 72 + t] = f2b(fmaxf(b2f(k.x), 0.f) + EPS_F);
        Kt[(d4 + 1) * 72 + t] = f2b(fmaxf(b2f(k.y), 0.f) + EPS_F);
        Kt[(d4 + 2) * 72 + t] = f2b(fmaxf(b2f(k.z), 0.f) + EPS_F);
        Kt[(d4 + 3) * 72 + t] = f2b(fmaxf(b2f(k.w), 0.f) + EPS_F);
        Vt[(d4 + 0) * 72 + t] = v.x;
        Vt[(d4 + 1) * 72 + t] = v.y;
        Vt[(d4 + 2) * 72 + t] = v.z;
        Vt[(d4 + 3) * 72 + t] = v.w;
    }
    __syncthreads();
    int wave = tid >> 6, lane = tid & 63;
    int lr = lane & 15, kg = lane >> 4;
    int wm = wave * 16;
    bf16x8 a0 = *(const bf16x8*)&Kt[(wm + lr) * 72 + kg * 8];
    bf16x8 a1 = *(const bf16x8*)&Kt[(wm + lr) * 72 + 32 + kg * 8];
    f32x4 acc[4] = {};
    #pragma unroll
    for (int j = 0; j < 4; j++) {
        bf16x8 b0 = *(const bf16x8*)&Vt[(j * 16 + lr) * 72 + kg * 8];
        bf16x8 b1 = *(const bf16x8*)&Vt[(j * 16 + lr) * 72 + 32 + kg * 8];
        acc[j] = __builtin_amdgcn_mfma_f32_16x16x32_bf16(a0, b0, acc[j], 0, 0, 0);
        acc[j] = __builtin_amdgcn_mfma_f32_16x16x32_bf16(a1, b1, acc[j], 0, 0, 0);
    }
    if (tid < 64) {
        float z = 0.f;
        #pragma unroll 8
        for (int t = 0; t < 64; t++) z += b2f(Kt[tid * 72 + t]);
        Z[(size_t)blk * 64 + tid] = z;
    }
    float* Sp = S + (size_t)blk * 4096;
    #pragma unroll
    for (int j = 0; j < 4; j++) {
        #pragma unroll
        for (int rr = 0; rr < 4; rr++) {
            int d = wm + kg * 4 + rr;
            int e = j * 16 + lr;
            Sp[d * 64 + e] = acc[j][rr];
        }
    }
}

// ---------------------------------------------------------------------------
// Pass B (fused exclusive prefix):
// o = (Q@KVstate + tril(Q@K^T)@V) / max(Q.kz + rowsum, 1e-6)
// ---------------------------------------------------------------------------
__global__ __launch_bounds__(256) void chunk_out_kernel(
    const u16* __restrict__ QKV, const float* __restrict__ S,
    const float* __restrict__ Z, u16* __restrict__ O)
{
    int blk = blockIdx.x;
    int c = blk % NC_;
    int bh = blk / NC_;
    int h = bh % H_;
    int b = bh / H_;
    __shared__ __align__(16) u16 Qb[64 * 72];    // [t][d]
    __shared__ __align__(16) u16 Kb[64 * 72];    // [t][d]
    __shared__ __align__(16) u16 Vt[64 * 72];    // [e][t]
    __shared__ __align__(16) u16 KVt[64 * 72];   // [e][d]
    __shared__ __align__(16) u16 Ps[64 * 72];    // [t][s]
    __shared__ float kzs[64];
    __shared__ float rows[64];
    __shared__ float invs[64];
    int tid = threadIdx.x;
    const size_t base = ((size_t)b * L_ + (size_t)c * CHK) * 768 + h * 64;
    const float* Sbh = S + (size_t)bh * NC_ * 4096;
    for (int i = tid; i < 1024; i += 256) {
        int t = i >> 4, d4 = (i & 15) << 2;
        ushort4 q = *(const ushort4*)(QKV + base + (size_t)t * 768 + d4);
        ushort4 k = *(const ushort4*)(QKV + base + (size_t)t * 768 + 256 + d4);
        ushort4 v = *(const ushort4*)(QKV + base + (size_t)t * 768 + 512 + d4);
        ushort4 qu, ku;
        qu.x = f2b(fmaxf(b2f(q.x), 0.f) + EPS_F); qu.y = f2b(fmaxf(b2f(q.y), 0.f) + EPS_F);
        qu.z = f2b(fmaxf(b2f(q.z), 0.f) + EPS_F); qu.w = f2b(fmaxf(b2f(q.w), 0.f) + EPS_F);
        ku.x = f2b(fmaxf(b2f(k.x), 0.f) + EPS_F); ku.y = f2b(fmaxf(b2f(k.y), 0.f) + EPS_F);
        ku.z = f2b(fmaxf(b2f(k.z), 0.f) + EPS_F); ku.w = f2b(fmaxf(b2f(k.w), 0.f) + EPS_F);
        *(ushort4*)&Qb[t * 72 + d4] = qu;
        *(ushort4*)&Kb[t * 72 + d4] = ku;
        Vt[(d4 + 0) * 72 + t] = v.x;
        Vt[(d4 + 1) * 72 + t] = v.y;
        Vt[(d4 + 2) * 72 + t] = v.z;
        Vt[(d4 + 3) * 72 + t] = v.w;
        int d = t, e4 = d4;
        float4 a = make_float4(0.f, 0.f, 0.f, 0.f);
        for (int cc = 0; cc < c; cc++) {
            float4 s4 = *(const float4*)(Sbh + (size_t)cc * 4096 + d * 64 + e4);
            a.x += s4.x; a.y += s4.y; a.z += s4.z; a.w += s4.w;
        }
        KVt[(e4 + 0) * 72 + d] = f2b(a.x);
        KVt[(e4 + 1) * 72 + d] = f2b(a.y);
        KVt[(e4 + 2) * 72 + d] = f2b(a.z);
        KVt[(e4 + 3) * 72 + d] = f2b(a.w);
    }
    if (tid < 64) {
        float z = 0.f;
        const float* Zbh = Z + (size_t)bh * NC_ * 64;
        for (int cc = 0; cc < c; cc++) z += Zbh[cc * 64 + tid];
        kzs[tid] = z;
    }
    __syncthreads();

    int wave = tid >> 6, lane = tid & 63;
    int lr = lane & 15, kg = lane >> 4;
    int wm = wave * 16;

    bf16x8 aq0 = *(const bf16x8*)&Qb[(wm + lr) * 72 + kg * 8];
    bf16x8 aq1 = *(const bf16x8*)&Qb[(wm + lr) * 72 + 32 + kg * 8];

    f32x4 accs[4] = {};
    #pragma unroll
    for (int j = 0; j < 4; j++) {
        bf16x8 b0 = *(const bf16x8*)&Kb[(j * 16 + lr) * 72 + kg * 8];
        bf16x8 b1 = *(const bf16x8*)&Kb[(j * 16 + lr) * 72 + 32 + kg * 8];
        accs[j] = __builtin_amdgcn_mfma_f32_16x16x32_bf16(aq0, b0, accs[j], 0, 0, 0);
        accs[j] = __builtin_amdgcn_mfma_f32_16x16x32_bf16(aq1, b1, accs[j], 0, 0, 0);
    }
    float rsum[4] = {0.f, 0.f, 0.f, 0.f};
    #pragma unroll
    for (int j = 0; j < 4; j++) {
        #pragma unroll
        for (int rr = 0; rr < 4; rr++) {
            int m = wm + kg * 4 + rr;
            int n = j * 16 + lr;
            float v = (n <= m) ? accs[j][rr] : 0.f;
            rsum[rr] += v;
            Ps[m * 72 + n] = f2b(v);
        }
    }
    #pragma unroll
    for (int rr = 0; rr < 4; rr++) {
        float s = rsum[rr];
        s += __shfl_xor(s, 1, 64);
        s += __shfl_xor(s, 2, 64);
        s += __shfl_xor(s, 4, 64);
        s += __shfl_xor(s, 8, 64);
        if (lr == 0) rows[wm + kg * 4 + rr] = s;
    }
    __syncthreads();

    if (tid < 64) {
        float den = rows[tid];
        float acc = 0.f;
        #pragma unroll 8
        for (int d = 0; d < 64; d++) acc += b2f(Qb[tid * 72 + d]) * kzs[d];
        invs[tid] = 1.f / fmaxf(den + acc, 1e-6f);
    }

    bf16x8 ap0 = *(const bf16x8*)&Ps[(wm + lr) * 72 + kg * 8];
    bf16x8 ap1 = *(const bf16x8*)&Ps[(wm + lr) * 72 + 32 + kg * 8];
    f32x4 accn[4] = {};
    #pragma unroll
    for (int j = 0; j < 4; j++) {
        bf16x8 b0 = *(const bf16x8*)&KVt[(j * 16 + lr) * 72 + kg * 8];
        bf16x8 b1 = *(const bf16x8*)&KVt[(j * 16 + lr) * 72 + 32 + kg * 8];
        accn[j] = __builtin_amdgcn_mfma_f32_16x16x32_bf16(aq0, b0, accn[j], 0, 0, 0);
        accn[j] = __builtin_amdgcn_mfma_f32_16x16x32_bf16(aq1, b1, accn[j], 0, 0, 0);
        bf16x8 c0 = *(const bf16x8*)&Vt[(j * 16 + lr) * 72 + kg * 8];
        bf16x8 c1 = *(const bf16x8*)&Vt[(j * 16 + lr) * 72 + 32 + kg * 8];
        accn[j] = __builtin_amdgcn_mfma_f32_16x16x32_bf16(ap0, c0, accn[j], 0, 0, 0);
        accn[j] = __builtin_amdgcn_mfma_f32_16x16x32_bf16(ap1, c1, accn[j], 0, 0, 0);
    }
    __syncthreads();

    u16* Op = O + ((size_t)b * L_ + (size_t)c * CHK) * E_ + h * 64;
    #pragma unroll
    for (int j = 0; j < 4; j++) {
        #pragma unroll
        for (int rr = 0; rr < 4; rr++) {
            int m = wm + kg * 4 + rr;
            int e = j * 16 + lr;
            Op[(size_t)m * E_ + e] = f2b(accn[j][rr] * invs[m]);
        }
    }
}

// ---------------------------------------------------------------------------
// Final LN + prediction head, state tokens only. One wave per state token.
// ---------------------------------------------------------------------------
__global__ __launch_bounds__(256) void lnpred_kernel(
    const float* __restrict__ X, const float* __restrict__ g,
    const float* __restrict__ bt, const float* __restrict__ W,
    const float* __restrict__ bias, float* __restrict__ Out)
{
    int si = blockIdx.x * 4 + (threadIdx.x >> 6);   // 0..1023 state index
    int lane = threadIdx.x & 63;
    int b = si / K_, t = si % K_;
    size_t row = (size_t)b * L_ + 3 * t + 1;
    int e0 = lane * 4;
    float4 v = *(const float4*)(X + row * E_ + e0);
    float s = v.x + v.y + v.z + v.w;
    #pragma unroll
    for (int o = 32; o; o >>= 1) s += __shfl_xor(s, o, 64);
    float mean = s * (1.f / E_);
    float dx = v.x - mean, dy = v.y - mean, dz = v.z - mean, dw = v.w - mean;
    float q = dx * dx + dy * dy + dz * dz + dw * dw;
    #pragma unroll
    for (int o = 32; o; o >>= 1) q += __shfl_xor(q, o, 64);
    float inv = rsqrtf(q * (1.f / E_) + LN_EPS);
    float4 gv = *(const float4*)(g + e0);
    float4 bv = *(const float4*)(bt + e0);
    float y0 = dx * inv * gv.x + bv.x;
    float y1 = dy * inv * gv.y + bv.y;
    float y2 = dz * inv * gv.z + bv.z;
    float y3 = dw * inv * gv.w + bv.w;
    #pragma unroll
    for (int na = 0; na < NA_; na++) {
        float a = y0 * W[(e0 + 0) * NA_ + na] + y1 * W[(e0 + 1) * NA_ + na]
                + y2 * W[(e0 + 2) * NA_ + na] + y3 * W[(e0 + 3) * NA_ + na];
        #pragma unroll
        for (int o = 32; o; o >>= 1) a += __shfl_xor(a, o, 64);
        if (lane == 0) Out[(size_t)si * NA_ + na] = a + bias[na];
    }
}

// ---------------------------------------------------------------------------
extern "C" void kernel_launch(void* const* d_in, const int* in_sizes, int n_in,
                              void* d_out, int out_size, void* d_ws, size_t ws_size,
                              hipStream_t stream) {
    const float* rtg      = (const float*)d_in[0];
    const float* state    = (const float*)d_in[1];
    const float* action   = (const float*)d_in[2];
    const float* rtg_w    = (const float*)d_in[3];
    const float* rtg_b    = (const float*)d_in[4];
    const float* state_w  = (const float*)d_in[5];
    const float* state_b  = (const float*)d_in[6];
    const float* action_w = (const float*)d_in[7];
    const float* action_b = (const float*)d_in[8];
    const float* pos_emb  = (const float*)d_in[9];
    const float* norm1_g  = (const float*)d_in[10];
    const float* norm1_b  = (const float*)d_in[11];
    const float* qkv_w    = (const float*)d_in[12];
    const float* qkv_b    = (const float*)d_in[13];
    const float* out_w    = (const float*)d_in[14];
    const float* out_b    = (const float*)d_in[15];
    const float* norm2_g  = (const float*)d_in[16];
    const float* norm2_b  = (const float*)d_in[17];
    const float* ffn1_w   = (const float*)d_in[18];
    const float* ffn1_b   = (const float*)d_in[19];
    const float* ffn2_w   = (const float*)d_in[20];
    const float* ffn2_b   = (const float*)d_in[21];
    const float* normf_g  = (const float*)d_in[22];
    const float* normf_b  = (const float*)d_in[23];
    const float* pred_w   = (const float*)d_in[24];
    const float* pred_b   = (const float*)d_in[25];
    float* out = (float*)d_out;

    // workspace layout
    float* ws = (float*)d_ws;
    float* x    = ws;                        // 786432 f
    float* S    = x + 786432;                // 786432 f
    float* Z    = S + 786432;                // 12288 f
    u16*   yb   = (u16*)(Z + 12288);         // 786432 u16
    u16*   qkvb = yb + 786432;               // 2359296 u16
    u16*   att  = qkvb + 2359296;            // 786432
    u16*   h1   = att + 786432;              // 3145728
    u16*   qkvT = h1 + 3145728;              // 393216
    u16*   outT = qkvT + 393216;             // 131072
    u16*   f1T  = outT + 131072;             // 524288
    u16*   f2T  = f1T + 524288;              // 524288

    init_kernel<<<2304, 256, 0, stream>>>(
        qkv_w, out_w, ffn1_w, ffn2_w, qkvT, outT, f1T, f2T,
        rtg, state, action, rtg_w, rtg_b, state_w, state_b,
        action_w, action_b, pos_emb, norm1_g, norm1_b, x, yb);

    for (int i = 0; i < NL_; i++) {
        mgemm<0><<<dim3(768 / 128, M_ / 128), 256, 0, stream>>>(
            yb, qkvT + (size_t)i * 196608, qkv_b + i * 768, qkvb,
            M_, 768, E_);
        chunk_sum_kernel<<<B_ * H_ * NC_, 256, 0, stream>>>(qkvb, S, Z);
        chunk_out_kernel<<<B_ * H_ * NC_, 256, 0, stream>>>(qkvb, S, Z, att);
        gemm64res<<<M_ / 64 * 4, 256, 0, stream>>>(
            att, outT + (size_t)i * 65536, out_b + i * E_, x, E_);
        ln_kernel<<<M_ / 4, 256, 0, stream>>>(
            x, norm2_g + i * E_, norm2_b + i * E_, yb);
        mgemm<1><<<dim3(FF_ / 128, M_ / 128), 256, 0, stream>>>(
            yb, f1T + (size_t)i * 262144, ffn1_b + i * FF_, h1,
            M_, FF_, E_);
        gemm64res<<<M_ / 64 * 4, 256, 0, stream>>>(
            h1, f2T + (size_t)i * 262144, ffn2_b + i * E_, x, FF_);
        if (i == 0)
            ln_kernel<<<M_ / 4, 256, 0, stream>>>(
                x, norm1_g + E_, norm1_b + E_, yb);
    }
    lnpred_kernel<<<(B_ * K_) / 4, 256, 0, stream>>>(
        x, normf_g, normf_b, pred_w, pred_b, out);
}

// Round 11
// 275.151 us; speedup vs baseline: 1.2739x; 1.2739x over previous
//
#include <hip/hip_runtime.h>
#include <hip/hip_bf16.h>
#include <math.h>

// Problem constants
#define B_  2
#define K_  512
#define SD_ 60
#define NA_ 5
#define E_  256
#define H_  4
#define D_  64
#define FF_ 1024
#define NL_ 2
#define L_  (3 * K_)          // 1536 tokens per batch
#define M_  (B_ * L_)         // 3072 rows total
#define EPS_F 1e-6f
#define LN_EPS 1e-5f
#define CHK 64
#define NC_ (L_ / CHK)        // 24 chunks per (b,h)

using bf16x8 = __attribute__((ext_vector_type(8))) short;
using f32x4  = __attribute__((ext_vector_type(4))) float;
typedef unsigned short u16;

__device__ inline u16 f2b(float v) {
    __hip_bfloat16 h = __float2bfloat16(v);
    return *(u16*)&h;
}
__device__ inline float b2f(u16 v) {
    __hip_bfloat16 h = *(__hip_bfloat16*)&v;
    return __bfloat162float(h);
}

// ---------------------------------------------------------------------------
// Init kernel: blocks 0..1535 = weight convert+transpose (32x32 tiles),
//              blocks 1536..2303 = embed + interleave + LN1(layer0)
// ---------------------------------------------------------------------------
__global__ __launch_bounds__(256) void init_kernel(
    const float* __restrict__ qkv_w, const float* __restrict__ out_w,
    const float* __restrict__ ffn1_w, const float* __restrict__ ffn2_w,
    u16* __restrict__ qkvT, u16* __restrict__ outT,
    u16* __restrict__ f1T, u16* __restrict__ f2T,
    const float* __restrict__ rtg, const float* __restrict__ state,
    const float* __restrict__ action,
    const float* __restrict__ rtg_w, const float* __restrict__ rtg_b,
    const float* __restrict__ state_w, const float* __restrict__ state_b,
    const float* __restrict__ action_w, const float* __restrict__ action_b,
    const float* __restrict__ pos,
    const float* __restrict__ g, const float* __restrict__ bta,
    float* __restrict__ X, u16* __restrict__ Y)
{
    __shared__ u16 T[32][33];
    if (blockIdx.x < 1536) {
        int tb = blockIdx.x;
        int layer = tb / 768;
        int r = tb % 768;
        const float* src; u16* dst; int K, N, tidx;
        if (r < 192)      { src = qkv_w  + layer * 196608; dst = qkvT + layer * 196608; K = 256;  N = 768;  tidx = r; }
        else if (r < 256) { src = out_w  + layer * 65536;  dst = outT + layer * 65536;  K = 256;  N = 256;  tidx = r - 192; }
        else if (r < 512) { src = ffn1_w + layer * 262144; dst = f1T  + layer * 262144; K = 256;  N = 1024; tidx = r - 256; }
        else              { src = ffn2_w + layer * 262144; dst = f2T  + layer * 262144; K = 1024; N = 256;  tidx = r - 512; }
        int tilesN = N >> 5;
        int k0 = (tidx / tilesN) << 5;
        int n0 = (tidx % tilesN) << 5;
        int c = threadIdx.x & 31, r0 = threadIdx.x >> 5;
        for (int rr = r0; rr < 32; rr += 8)
            T[rr][c] = f2b(src[(size_t)(k0 + rr) * N + n0 + c]);
        __syncthreads();
        for (int rr = r0; rr < 32; rr += 8)
            dst[(size_t)(n0 + rr) * K + k0 + c] = T[c][rr];
        return;
    }
    // embed + LN1(layer0)
    int tok = (blockIdx.x - 1536) * 4 + (threadIdx.x >> 6);
    int lane = threadIdx.x & 63;
    int b = tok / L_, l = tok % L_;
    int j = l % 3, t = l / 3;
    int e0 = lane * 4;
    float4 val = *(const float4*)(pos + t * E_ + e0);
    if (j == 0) {
        float rv = rtg[b * K_ + t];
        float4 w = *(const float4*)(rtg_w + e0);
        float4 bb = *(const float4*)(rtg_b + e0);
        val.x += rv * w.x + bb.x; val.y += rv * w.y + bb.y;
        val.z += rv * w.z + bb.z; val.w += rv * w.w + bb.w;
    } else if (j == 1) {
        float4 a = *(const float4*)(state_b + e0);
        const float* srow = state + ((size_t)b * K_ + t) * SD_;
        for (int i = 0; i < SD_; i++) {
            float s = srow[i];
            float4 w = *(const float4*)(state_w + (size_t)i * E_ + e0);
            a.x += s * w.x; a.y += s * w.y; a.z += s * w.z; a.w += s * w.w;
        }
        val.x += a.x; val.y += a.y; val.z += a.z; val.w += a.w;
    } else {
        float4 a = *(const float4*)(action_b + e0);
        const float* arow = action + ((size_t)b * K_ + t) * NA_;
        #pragma unroll
        for (int i = 0; i < NA_; i++) {
            float s = arow[i];
            float4 w = *(const float4*)(action_w + (size_t)i * E_ + e0);
            a.x += s * w.x; a.y += s * w.y; a.z += s * w.z; a.w += s * w.w;
        }
        val.x += a.x; val.y += a.y; val.z += a.z; val.w += a.w;
    }
    *(float4*)(X + (size_t)tok * E_ + e0) = val;
    float s = val.x + val.y + val.z + val.w;
    #pragma unroll
    for (int o = 32; o; o >>= 1) s += __shfl_xor(s, o, 64);
    float mean = s * (1.f / E_);
    float dx = val.x - mean, dy = val.y - mean, dz = val.z - mean, dw = val.w - mean;
    float q = dx * dx + dy * dy + dz * dz + dw * dw;
    #pragma unroll
    for (int o = 32; o; o >>= 1) q += __shfl_xor(q, o, 64);
    float inv = rsqrtf(q * (1.f / E_) + LN_EPS);
    float4 gv = *(const float4*)(g + e0);
    float4 bv = *(const float4*)(bta + e0);
    ushort4 u;
    u.x = f2b(dx * inv * gv.x + bv.x); u.y = f2b(dy * inv * gv.y + bv.y);
    u.z = f2b(dz * inv * gv.z + bv.z); u.w = f2b(dw * inv * gv.w + bv.w);
    *(ushort4*)(Y + (size_t)tok * E_ + e0) = u;
}

// ---------------------------------------------------------------------------
// LayerNorm over E=256; one wave per token, fp32 in, bf16 out
// ---------------------------------------------------------------------------
__global__ __launch_bounds__(256) void ln_kernel(
    const float* __restrict__ X, const float* __restrict__ g,
    const float* __restrict__ b, u16* __restrict__ Y)
{
    int tok = blockIdx.x * 4 + (threadIdx.x >> 6);
    int lane = threadIdx.x & 63;
    int e0 = lane * 4;
    float4 v = *(const float4*)(X + (size_t)tok * E_ + e0);
    float s = v.x + v.y + v.z + v.w;
    #pragma unroll
    for (int o = 32; o; o >>= 1) s += __shfl_xor(s, o, 64);
    float mean = s * (1.f / E_);
    float dx = v.x - mean, dy = v.y - mean, dz = v.z - mean, dw = v.w - mean;
    float q = dx * dx + dy * dy + dz * dz + dw * dw;
    #pragma unroll
    for (int o = 32; o; o >>= 1) q += __shfl_xor(q, o, 64);
    float inv = rsqrtf(q * (1.f / E_) + LN_EPS);
    float4 gv = *(const float4*)(g + e0);
    float4 bv = *(const float4*)(b + e0);
    ushort4 u;
    u.x = f2b(dx * inv * gv.x + bv.x); u.y = f2b(dy * inv * gv.y + bv.y);
    u.z = f2b(dz * inv * gv.z + bv.z); u.w = f2b(dw * inv * gv.w + bv.w);
    *(ushort4*)(Y + (size_t)tok * E_ + e0) = u;
}

// ---------------------------------------------------------------------------
// MFMA bf16 GEMM: C[M,N] = epi(A[M,K]bf16 @ Bt[N,K]bf16^T + bias), bf16 out
// 128x128 tile, 256 threads = 4 waves (2x2 of 64x64), BK=32
// EPI: 0 none, 1 exact gelu
// ---------------------------------------------------------------------------
template <int EPI>
__global__ __launch_bounds__(256) void mgemm(
    const u16* __restrict__ A, const u16* __restrict__ Bt,
    const float* __restrict__ bias,
    u16* __restrict__ C, int M, int N, int Kd)
{
    __shared__ __align__(16) u16 As[128 * 40];
    __shared__ __align__(16) u16 Bs[128 * 40];
    int tid = threadIdx.x;
    int bm = blockIdx.y * 128, bn = blockIdx.x * 128;
    int wave = tid >> 6, lane = tid & 63;
    int wm = (wave >> 1) * 64, wn = (wave & 1) * 64;
    int lr = lane & 15, kg = lane >> 4;

    int r0 = tid >> 2, g0 = (tid & 3) * 8;
    int r1 = (tid + 256) >> 2, g1 = (tid & 3) * 8;

    f32x4 acc[4][4] = {};

    for (int k0 = 0; k0 < Kd; k0 += 32) {
        uint4 a0 = *(const uint4*)(A + (size_t)(bm + r0) * Kd + k0 + g0);
        uint4 a1 = *(const uint4*)(A + (size_t)(bm + r1) * Kd + k0 + g1);
        uint4 b0 = *(const uint4*)(Bt + (size_t)(bn + r0) * Kd + k0 + g0);
        uint4 b1 = *(const uint4*)(Bt + (size_t)(bn + r1) * Kd + k0 + g1);
        __syncthreads();
        *(uint4*)&As[r0 * 40 + g0] = a0;
        *(uint4*)&As[r1 * 40 + g1] = a1;
        *(uint4*)&Bs[r0 * 40 + g0] = b0;
        *(uint4*)&Bs[r1 * 40 + g1] = b1;
        __syncthreads();
        bf16x8 af[4], bg[4];
        #pragma unroll
        for (int i = 0; i < 4; i++)
            af[i] = *(const bf16x8*)&As[(wm + i * 16 + lr) * 40 + kg * 8];
        #pragma unroll
        for (int j = 0; j < 4; j++)
            bg[j] = *(const bf16x8*)&Bs[(wn + j * 16 + lr) * 40 + kg * 8];
        #pragma unroll
        for (int i = 0; i < 4; i++)
            #pragma unroll
            for (int j = 0; j < 4; j++)
                acc[i][j] = __builtin_amdgcn_mfma_f32_16x16x32_bf16(
                    af[i], bg[j], acc[i][j], 0, 0, 0);
    }

    #pragma unroll
    for (int i = 0; i < 4; i++) {
        #pragma unroll
        for (int j = 0; j < 4; j++) {
            int col = bn + wn + j * 16 + lr;
            float bc = bias[col];
            #pragma unroll
            for (int r = 0; r < 4; r++) {
                int row = bm + wm + i * 16 + kg * 4 + r;
                float v = acc[i][j][r] + bc;
                if (EPI == 1) v = 0.5f * v * (1.0f + erff(v * 0.70710678118654752f));
                C[(size_t)row * N + col] = f2b(v);
            }
        }
    }
}

// ---------------------------------------------------------------------------
// 64x64-tile MFMA GEMM + residual accumulate into fp32 X. N=256 fixed.
// 192 tiles (M/64 x 4); 4 waves as 2x2 of 32x32. BK=32.
// ---------------------------------------------------------------------------
__global__ __launch_bounds__(256) void gemm64res(
    const u16* __restrict__ A, const u16* __restrict__ Bt,
    const float* __restrict__ bias, float* __restrict__ X, int Kd)
{
    __shared__ __align__(16) u16 As[64 * 40];
    __shared__ __align__(16) u16 Bs[64 * 40];
    int tid = threadIdx.x;
    int tile = blockIdx.x;
    int bm = (tile >> 2) * 64, bn = (tile & 3) * 64;
    int wave = tid >> 6, lane = tid & 63;
    int wm = (wave >> 1) * 32, wn = (wave & 1) * 32;
    int lr = lane & 15, kg = lane >> 4;
    int r = tid >> 2, g = (tid & 3) * 8;

    f32x4 acc[2][2] = {};
    for (int k0 = 0; k0 < Kd; k0 += 32) {
        uint4 a0 = *(const uint4*)(A + (size_t)(bm + r) * Kd + k0 + g);
        uint4 b0 = *(const uint4*)(Bt + (size_t)(bn + r) * Kd + k0 + g);
        __syncthreads();
        *(uint4*)&As[r * 40 + g] = a0;
        *(uint4*)&Bs[r * 40 + g] = b0;
        __syncthreads();
        bf16x8 af[2], bg[2];
        #pragma unroll
        for (int i = 0; i < 2; i++)
            af[i] = *(const bf16x8*)&As[(wm + i * 16 + lr) * 40 + kg * 8];
        #pragma unroll
        for (int j = 0; j < 2; j++)
            bg[j] = *(const bf16x8*)&Bs[(wn + j * 16 + lr) * 40 + kg * 8];
        #pragma unroll
        for (int i = 0; i < 2; i++)
            #pragma unroll
            for (int j = 0; j < 2; j++)
                acc[i][j] = __builtin_amdgcn_mfma_f32_16x16x32_bf16(
                    af[i], bg[j], acc[i][j], 0, 0, 0);
    }
    #pragma unroll
    for (int i = 0; i < 2; i++) {
        #pragma unroll
        for (int j = 0; j < 2; j++) {
            int col = bn + wn + j * 16 + lr;
            float bc = bias[col];
            #pragma unroll
            for (int rr = 0; rr < 4; rr++) {
                int row = bm + wm + i * 16 + kg * 4 + rr;
                float v = acc[i][j][rr] + bc + X[(size_t)row * 256 + col];
                X[(size_t)row * 256 + col] = v;
            }
        }
    }
}

// ---------------------------------------------------------------------------
// Chunked linear attention; qkv bf16: (B,L,768) q|k|v head-major D=64
// Pass A: per-chunk S[d][e] = sum_t k[t][d] v[t][e], z[d] = sum_t k[t][d]
// ---------------------------------------------------------------------------
__global__ __launch_bounds__(256) void chunk_sum_kernel(
    const u16* __restrict__ QKV, float* __restrict__ S, float* __restrict__ Z)
{
    int blk = blockIdx.x;                  // (b*H+h)*NC + c
    int c = blk % NC_;
    int bh = blk / NC_;
    int h = bh % H_;
    int b = bh / H_;
    __shared__ __align__(16) u16 Kt[64 * 72];   // [d][t]
    __shared__ __align__(16) u16 Vt[64 * 72];   // [e][t]
    int tid = threadIdx.x;
    const size_t base = ((size_t)b * L_ + (size_t)c * CHK) * 768 + h * 64;
    for (int i = tid; i < 1024; i += 256) {
        int t = i >> 4, d4 = (i & 15) << 2;
        ushort4 k = *(const ushort4*)(QKV + base + (size_t)t * 768 + 256 + d4);
        ushort4 v = *(const ushort4*)(QKV + base + (size_t)t * 768 + 512 + d4);
        Kt[(d4 + 0) * 72 + t] = f2b(fmaxf(b2f(k.x), 0.f) + EPS_F);
        Kt[(d4 + 1) * 72 + t] = f2b(fmaxf(b2f(k.y), 0.f) + EPS_F);
        Kt[(d4 + 2) * 72 + t] = f2b(fmaxf(b2f(k.z), 0.f) + EPS_F);
        Kt[(d4 + 3) * 72 + t] = f2b(fmaxf(b2f(k.w), 0.f) + EPS_F);
        Vt[(d4 + 0) * 72 + t] = v.x;
        Vt[(d4 + 1) * 72 + t] = v.y;
        Vt[(d4 + 2) * 72 + t] = v.z;
        Vt[(d4 + 3) * 72 + t] = v.w;
    }
    __syncthreads();
    int wave = tid >> 6, lane = tid & 63;
    int lr = lane & 15, kg = lane >> 4;
    int wm = wave * 16;
    bf16x8 a0 = *(const bf16x8*)&Kt[(wm + lr) * 72 + kg * 8];
    bf16x8 a1 = *(const bf16x8*)&Kt[(wm + lr) * 72 + 32 + kg * 8];
    f32x4 acc[4] = {};
    #pragma unroll
    for (int j = 0; j < 4; j++) {
        bf16x8 b0 = *(const bf16x8*)&Vt[(j * 16 + lr) * 72 + kg * 8];
        bf16x8 b1 = *(const bf16x8*)&Vt[(j * 16 + lr) * 72 + 32 + kg * 8];
        acc[j] = __builtin_amdgcn_mfma_f32_16x16x32_bf16(a0, b0, acc[j], 0, 0, 0);
        acc[j] = __builtin_amdgcn_mfma_f32_16x16x32_bf16(a1, b1, acc[j], 0, 0, 0);
    }
    if (tid < 64) {
        float z = 0.f;
        #pragma unroll 8
        for (int t = 0; t < 64; t++) z += b2f(Kt[tid * 72 + t]);
        Z[(size_t)blk * 64 + tid] = z;
    }
    float* Sp = S + (size_t)blk * 4096;
    #pragma unroll
    for (int j = 0; j < 4; j++) {
        #pragma unroll
        for (int rr = 0; rr < 4; rr++) {
            int d = wm + kg * 4 + rr;
            int e = j * 16 + lr;
            Sp[d * 64 + e] = acc[j][rr];
        }
    }
}

// ---------------------------------------------------------------------------
// Pass B (fused exclusive prefix):
// o = (Q@KVstate + tril(Q@K^T)@V) / max(Q.kz + rowsum, 1e-6)
// ---------------------------------------------------------------------------
__global__ __launch_bounds__(256) void chunk_out_kernel(
    const u16* __restrict__ QKV, const float* __restrict__ S,
    const float* __restrict__ Z, u16* __restrict__ O)
{
    int blk = blockIdx.x;
    int c = blk % NC_;
    int bh = blk / NC_;
    int h = bh % H_;
    int b = bh / H_;
    __shared__ __align__(16) u16 Qb[64 * 72];    // [t][d]
    __shared__ __align__(16) u16 Kb[64 * 72];    // [t][d]
    __shared__ __align__(16) u16 Vt[64 * 72];    // [e][t]
    __shared__ __align__(16) u16 KVt[64 * 72];   // [e][d]
    __shared__ __align__(16) u16 Ps[64 * 72];    // [t][s]
    __shared__ float kzs[64];
    __shared__ float rows[64];
    __shared__ float invs[64];
    int tid = threadIdx.x;
    const size_t base = ((size_t)b * L_ + (size_t)c * CHK) * 768 + h * 64;
    const float* Sbh = S + (size_t)bh * NC_ * 4096;
    for (int i = tid; i < 1024; i += 256) {
        int t = i >> 4, d4 = (i & 15) << 2;
        ushort4 q = *(const ushort4*)(QKV + base + (size_t)t * 768 + d4);
        ushort4 k = *(const ushort4*)(QKV + base + (size_t)t * 768 + 256 + d4);
        ushort4 v = *(const ushort4*)(QKV + base + (size_t)t * 768 + 512 + d4);
        ushort4 qu, ku;
        qu.x = f2b(fmaxf(b2f(q.x), 0.f) + EPS_F); qu.y = f2b(fmaxf(b2f(q.y), 0.f) + EPS_F);
        qu.z = f2b(fmaxf(b2f(q.z), 0.f) + EPS_F); qu.w = f2b(fmaxf(b2f(q.w), 0.f) + EPS_F);
        ku.x = f2b(fmaxf(b2f(k.x), 0.f) + EPS_F); ku.y = f2b(fmaxf(b2f(k.y), 0.f) + EPS_F);
        ku.z = f2b(fmaxf(b2f(k.z), 0.f) + EPS_F); ku.w = f2b(fmaxf(b2f(k.w), 0.f) + EPS_F);
        *(ushort4*)&Qb[t * 72 + d4] = qu;
        *(ushort4*)&Kb[t * 72 + d4] = ku;
        Vt[(d4 + 0) * 72 + t] = v.x;
        Vt[(d4 + 1) * 72 + t] = v.y;
        Vt[(d4 + 2) * 72 + t] = v.z;
        Vt[(d4 + 3) * 72 + t] = v.w;
        int d = t, e4 = d4;
        float4 a = make_float4(0.f, 0.f, 0.f, 0.f);
        for (int cc = 0; cc < c; cc++) {
            float4 s4 = *(const float4*)(Sbh + (size_t)cc * 4096 + d * 64 + e4);
            a.x += s4.x; a.y += s4.y; a.z += s4.z; a.w += s4.w;
        }
        KVt[(e4 + 0) * 72 + d] = f2b(a.x);
        KVt[(e4 + 1) * 72 + d] = f2b(a.y);
        KVt[(e4 + 2) * 72 + d] = f2b(a.z);
        KVt[(e4 + 3) * 72 + d] = f2b(a.w);
    }
    if (tid < 64) {
        float z = 0.f;
        const float* Zbh = Z + (size_t)bh * NC_ * 64;
        for (int cc = 0; cc < c; cc++) z += Zbh[cc * 64 + tid];
        kzs[tid] = z;
    }
    __syncthreads();

    int wave = tid >> 6, lane = tid & 63;
    int lr = lane & 15, kg = lane >> 4;
    int wm = wave * 16;

    bf16x8 aq0 = *(const bf16x8*)&Qb[(wm + lr) * 72 + kg * 8];
    bf16x8 aq1 = *(const bf16x8*)&Qb[(wm + lr) * 72 + 32 + kg * 8];

    f32x4 accs[4] = {};
    #pragma unroll
    for (int j = 0; j < 4; j++) {
        bf16x8 b0 = *(const bf16x8*)&Kb[(j * 16 + lr) * 72 + kg * 8];
        bf16x8 b1 = *(const bf16x8*)&Kb[(j * 16 + lr) * 72 + 32 + kg * 8];
        accs[j] = __builtin_amdgcn_mfma_f32_16x16x32_bf16(aq0, b0, accs[j], 0, 0, 0);
        accs[j] = __builtin_amdgcn_mfma_f32_16x16x32_bf16(aq1, b1, accs[j], 0, 0, 0);
    }
    float rsum[4] = {0.f, 0.f, 0.f, 0.f};
    #pragma unroll
    for (int j = 0; j < 4; j++) {
        #pragma unroll
        for (int rr = 0; rr < 4; rr++) {
            int m = wm + kg * 4 + rr;
            int n = j * 16 + lr;
            float v = (n <= m) ? accs[j][rr] : 0.f;
            rsum[rr] += v;
            Ps[m * 72 + n] = f2b(v);
        }
    }
    #pragma unroll
    for (int rr = 0; rr < 4; rr++) {
        float s = rsum[rr];
        s += __shfl_xor(s, 1, 64);
        s += __shfl_xor(s, 2, 64);
        s += __shfl_xor(s, 4, 64);
        s += __shfl_xor(s, 8, 64);
        if (lr == 0) rows[wm + kg * 4 + rr] = s;
    }
    __syncthreads();

    if (tid < 64) {
        float den = rows[tid];
        float acc = 0.f;
        #pragma unroll 8
        for (int d = 0; d < 64; d++) acc += b2f(Qb[tid * 72 + d]) * kzs[d];
        invs[tid] = 1.f / fmaxf(den + acc, 1e-6f);
    }

    bf16x8 ap0 = *(const bf16x8*)&Ps[(wm + lr) * 72 + kg * 8];
    bf16x8 ap1 = *(const bf16x8*)&Ps[(wm + lr) * 72 + 32 + kg * 8];
    f32x4 accn[4] = {};
    #pragma unroll
    for (int j = 0; j < 4; j++) {
        bf16x8 b0 = *(const bf16x8*)&KVt[(j * 16 + lr) * 72 + kg * 8];
        bf16x8 b1 = *(const bf16x8*)&KVt[(j * 16 + lr) * 72 + 32 + kg * 8];
        accn[j] = __builtin_amdgcn_mfma_f32_16x16x32_bf16(aq0, b0, accn[j], 0, 0, 0);
        accn[j] = __builtin_amdgcn_mfma_f32_16x16x32_bf16(aq1, b1, accn[j], 0, 0, 0);
        bf16x8 c0 = *(const bf16x8*)&Vt[(j * 16 + lr) * 72 + kg * 8];
        bf16x8 c1 = *(const bf16x8*)&Vt[(j * 16 + lr) * 72 + 32 + kg * 8];
        accn[j] = __builtin_amdgcn_mfma_f32_16x16x32_bf16(ap0, c0, accn[j], 0, 0, 0);
        accn[j] = __builtin_amdgcn_mfma_f32_16x16x32_bf16(ap1, c1, accn[j], 0, 0, 0);
    }
    __syncthreads();

    u16* Op = O + ((size_t)b * L_ + (size_t)c * CHK) * E_ + h * 64;
    #pragma unroll
    for (int j = 0; j < 4; j++) {
        #pragma unroll
        for (int rr = 0; rr < 4; rr++) {
            int m = wm + kg * 4 + rr;
            int e = j * 16 + lr;
            Op[(size_t)m * E_ + e] = f2b(accn[j][rr] * invs[m]);
        }
    }
}

// ---------------------------------------------------------------------------
// Final LN + prediction head, state tokens only. One wave per state token.
// ---------------------------------------------------------------------------
__global__ __launch_bounds__(256) void lnpred_kernel(
    const float* __restrict__ X, const float* __restrict__ g,
    const float* __restrict__ bt, const float* __restrict__ W,
    const float* __restrict__ bias, float* __restrict__ Out)
{
    int si = blockIdx.x * 4 + (threadIdx.x >> 6);   // 0..1023 state index
    int lane = threadIdx.x & 63;
    int b = si / K_, t = si % K_;
    size_t row = (size_t)b * L_ + 3 * t + 1;
    int e0 = lane * 4;
    float4 v = *(const float4*)(X + row * E_ + e0);
    float s = v.x + v.y + v.z + v.w;
    #pragma unroll
    for (int o = 32; o; o >>= 1) s += __shfl_xor(s, o, 64);
    float mean = s * (1.f / E_);
    float dx = v.x - mean, dy = v.y - mean, dz = v.z - mean, dw = v.w - mean;
    float q = dx * dx + dy * dy + dz * dz + dw * dw;
    #pragma unroll
    for (int o = 32; o; o >>= 1) q += __shfl_xor(q, o, 64);
    float inv = rsqrtf(q * (1.f / E_) + LN_EPS);
    float4 gv = *(const float4*)(g + e0);
    float4 bv = *(const float4*)(bt + e0);
    float y0 = dx * inv * gv.x + bv.x;
    float y1 = dy * inv * gv.y + bv.y;
    float y2 = dz * inv * gv.z + bv.z;
    float y3 = dw * inv * gv.w + bv.w;
    #pragma unroll
    for (int na = 0; na < NA_; na++) {
        float a = y0 * W[(e0 + 0) * NA_ + na] + y1 * W[(e0 + 1) * NA_ + na]
                + y2 * W[(e0 + 2) * NA_ + na] + y3 * W[(e0 + 3) * NA_ + na];
        #pragma unroll
        for (int o = 32; o; o >>= 1) a += __shfl_xor(a, o, 64);
        if (lane == 0) Out[(size_t)si * NA_ + na] = a + bias[na];
    }
}

// ---------------------------------------------------------------------------
extern "C" void kernel_launch(void* const* d_in, const int* in_sizes, int n_in,
                              void* d_out, int out_size, void* d_ws, size_t ws_size,
                              hipStream_t stream) {
    const float* rtg      = (const float*)d_in[0];
    const float* state    = (const float*)d_in[1];
    const float* action   = (const float*)d_in[2];
    const float* rtg_w    = (const float*)d_in[3];
    const float* rtg_b    = (const float*)d_in[4];
    const float* state_w  = (const float*)d_in[5];
    const float* state_b  = (const float*)d_in[6];
    const float* action_w = (const float*)d_in[7];
    const float* action_b = (const float*)d_in[8];
    const float* pos_emb  = (const float*)d_in[9];
    const float* norm1_g  = (const float*)d_in[10];
    const float* norm1_b  = (const float*)d_in[11];
    const float* qkv_w    = (const float*)d_in[12];
    const float* qkv_b    = (const float*)d_in[13];
    const float* out_w    = (const float*)d_in[14];
    const float* out_b    = (const float*)d_in[15];
    const float* norm2_g  = (const float*)d_in[16];
    const float* norm2_b  = (const float*)d_in[17];
    const float* ffn1_w   = (const float*)d_in[18];
    const float* ffn1_b   = (const float*)d_in[19];
    const float* ffn2_w   = (const float*)d_in[20];
    const float* ffn2_b   = (const float*)d_in[21];
    const float* normf_g  = (const float*)d_in[22];
    const float* normf_b  = (const float*)d_in[23];
    const float* pred_w   = (const float*)d_in[24];
    const float* pred_b   = (const float*)d_in[25];
    float* out = (float*)d_out;

    // workspace layout
    float* ws = (float*)d_ws;
    float* x    = ws;                        // 786432 f
    float* S    = x + 786432;                // 786432 f
    float* Z    = S + 786432;                // 12288 f
    u16*   yb   = (u16*)(Z + 12288);         // 786432 u16
    u16*   qkvb = yb + 786432;               // 2359296 u16
    u16*   att  = qkvb + 2359296;            // 786432
    u16*   h1   = att + 786432;              // 3145728
    u16*   qkvT = h1 + 3145728;              // 393216
    u16*   outT = qkvT + 393216;             // 131072
    u16*   f1T  = outT + 131072;             // 524288
    u16*   f2T  = f1T + 524288;              // 524288

    init_kernel<<<2304, 256, 0, stream>>>(
        qkv_w, out_w, ffn1_w, ffn2_w, qkvT, outT, f1T, f2T,
        rtg, state, action, rtg_w, rtg_b, state_w, state_b,
        action_w, action_b, pos_emb, norm1_g, norm1_b, x, yb);

    for (int i = 0; i < NL_; i++) {
        mgemm<0><<<dim3(768 / 128, M_ / 128), 256, 0, stream>>>(
            yb, qkvT + (size_t)i * 196608, qkv_b + i * 768, qkvb,
            M_, 768, E_);
        chunk_sum_kernel<<<B_ * H_ * NC_, 256, 0, stream>>>(qkvb, S, Z);
        chunk_out_kernel<<<B_ * H_ * NC_, 256, 0, stream>>>(qkvb, S, Z, att);
        gemm64res<<<M_ / 64 * 4, 256, 0, stream>>>(
            att, outT + (size_t)i * 65536, out_b + i * E_, x, E_);
        ln_kernel<<<M_ / 4, 256, 0, stream>>>(
            x, norm2_g + i * E_, norm2_b + i * E_, yb);
        mgemm<1><<<dim3(FF_ / 128, M_ / 128), 256, 0, stream>>>(
            yb, f1T + (size_t)i * 262144, ffn1_b + i * FF_, h1,
            M_, FF_, E_);
        gemm64res<<<M_ / 64 * 4, 256, 0, stream>>>(
            h1, f2T + (size_t)i * 262144, ffn2_b + i * E_, x, FF_);
        if (i == 0)
            ln_kernel<<<M_ / 4, 256, 0, stream>>>(
                x, norm1_g + E_, norm1_b + E_, yb);
    }
    lnpred_kernel<<<(B_ * K_) / 4, 256, 0, stream>>>(
        x, normf_g, normf_b, pred_w, pred_b, out);
}